// Round 5
// baseline (95.138 us; speedup 1.0000x reference)
//
#include <hip/hip_runtime.h>
#include <hip/hip_bf16.h>

// ============================================================================
// AdaptiveDiffusionConv: out[b,n,o,t] = relu( sum_{k,f} Theta[k,f,o] * rhs_k )
//   rhs0 = x, rhs1 = a^T x, rhs2 = a^T rhs1   (a = adj .* spatial_attention)
// (a@a)^T x = a^T (a^T x)  -> two [1024x1024]^T @ [1024x192] batched GEMMs.
//
// R5 (= R4 + compile fix: short4 -> s16x4, HIP predefines short4):
// GEMM = 96x64 tile, 512 blocks (2/CU, 2 waves/SIMD), 3-deep global_load_lds
// pipeline, raw s_barrier + counted vmcnt(8), XOR-swizzled B staging,
// A direct global->reg prefetch. preps: float4 loads.
// ============================================================================

typedef __attribute__((ext_vector_type(8))) __bf16 bf16x8;
typedef __attribute__((ext_vector_type(4))) float  f32x4;
typedef __attribute__((ext_vector_type(8))) short  short8;
typedef __attribute__((ext_vector_type(4))) short  s16x4;

__device__ inline unsigned short f32_to_bf16(float f) {
    unsigned int u = __builtin_bit_cast(unsigned int, f);
    unsigned int r = u + 0x7FFFu + ((u >> 16) & 1u);   // RNE
    return (unsigned short)(r >> 16);
}
__device__ inline float bf16_to_f32(unsigned short u) {
    unsigned int x = ((unsigned int)u) << 16;
    return __builtin_bit_cast(float, x);
}

__device__ inline void gload_lds16(const void* gsrc, void* ldst) {
    __builtin_amdgcn_global_load_lds(
        (const __attribute__((address_space(1))) unsigned int*)gsrc,
        (__attribute__((address_space(3))) unsigned int*)ldst,
        16, 0, 0);
}

// ---------------------------------------------------------------------------
// prep_a: aT[b][n][m] = bf16(adj[m][n] * sa[b][m][n]); 32x32 tile transpose.
// float4 loads (16B/lane), ushort4 stores. grid (32 n, 32 m, 16 b) x 256.
// ---------------------------------------------------------------------------
__global__ void prep_a(const float* __restrict__ sa, const float* __restrict__ adj,
                       unsigned short* __restrict__ aT)
{
    __shared__ float tile[32][33];
    const int b  = blockIdx.z;
    const int m0 = blockIdx.y * 32;
    const int n0 = blockIdx.x * 32;
    const int tid = threadIdx.x;
    const int r  = tid >> 3;          // 0..31 (m-local)
    const int c4 = (tid & 7) * 4;     // n-local col group
    const float* sab = sa + (size_t)b * 1024 * 1024;

    size_t idx = (size_t)(m0 + r) * 1024 + (n0 + c4);
    f32x4 av = *reinterpret_cast<const f32x4*>(&adj[idx]);
    f32x4 sv = *reinterpret_cast<const f32x4*>(&sab[idx]);
#pragma unroll
    for (int k = 0; k < 4; k++) tile[r][c4 + k] = av[k] * sv[k];
    __syncthreads();

    unsigned short* aTb = aT + (size_t)b * 1024 * 1024;
    const int nl = tid >> 3;          // n-local row
    const int m4 = (tid & 7) * 4;     // m-local col group
    s16x4 v;
#pragma unroll
    for (int k = 0; k < 4; k++) v[k] = (short)f32_to_bf16(tile[m4 + k][nl]);
    *reinterpret_cast<s16x4*>(&aTb[(size_t)(n0 + nl) * 1024 + m0 + m4]) = v;
}

// ---------------------------------------------------------------------------
// prep_x: xT[b][j][m] = bf16(x[b][m][j]), j = f*12+t (192). float4 loads.
// grid (32 m, 6 j, 16 b) x 256.
// ---------------------------------------------------------------------------
__global__ void prep_x(const float* __restrict__ x, unsigned short* __restrict__ xT)
{
    __shared__ float tile[32][33];
    const int b  = blockIdx.z;
    const int j0 = blockIdx.y * 32;
    const int m0 = blockIdx.x * 32;
    const int tid = threadIdx.x;
    const int r  = tid >> 3;          // m-local
    const int c4 = (tid & 7) * 4;     // j-local
    const float* xb = x + (size_t)b * 1024 * 192;

    f32x4 v = *reinterpret_cast<const f32x4*>(&xb[(size_t)(m0 + r) * 192 + j0 + c4]);
#pragma unroll
    for (int k = 0; k < 4; k++) tile[r][c4 + k] = v[k];
    __syncthreads();

    unsigned short* xTb = xT + (size_t)b * 192 * 1024;
    const int jl = tid >> 3;
    const int m4 = (tid & 7) * 4;
    s16x4 o;
#pragma unroll
    for (int k = 0; k < 4; k++) o[k] = (short)f32_to_bf16(tile[m4 + k][jl]);
    *reinterpret_cast<s16x4*>(&xTb[(size_t)(j0 + jl) * 1024 + m0 + m4]) = o;
}

// ---------------------------------------------------------------------------
// gemm_tn: Cout[b][j][n] (bf16) = sum_m Aop[b][j][m] * Bop[b][n][m]
// tile 96j x 64n, BK=64, 4 waves (2x2), wave tile 48x32 (12 MFMA/step).
// 3 LDS buffers (24KB), raw s_barrier + counted vmcnt(8).
// grid (16 n, 2 j, 16 b) = 512 blocks -> 2 blocks/CU, 2 waves/SIMD.
// ---------------------------------------------------------------------------
__global__ __launch_bounds__(256, 2)
void gemm_tn(const unsigned short* __restrict__ Aop,
             const unsigned short* __restrict__ Bop,
             unsigned short* __restrict__ Cout)
{
    const int b  = blockIdx.z;
    const int j0 = blockIdx.y * 96;
    const int n0 = blockIdx.x * 64;
    const unsigned short* Ab = Aop + (size_t)b * 192 * 1024;
    const unsigned short* Bb = Bop + (size_t)b * 1024 * 1024;

    __shared__ unsigned short Blds[3][64 * 64];   // 3 x 8KB, linear

    const int tid  = threadIdx.x;
    const int lane = tid & 63;
    const int wave = tid >> 6;      // 0..3
    const int wj   = wave >> 1;     // 0..1 -> 48j
    const int wn   = wave & 1;      // 0..1 -> 32n
    const int lr   = lane & 15;
    const int lg   = lane >> 4;     // 0..3 (k-group)

    // staging: instr i stages chunk c = wave + i*4 (rows 8c..8c+7, 1KB);
    // lane covers row 8c+(lane>>3), dest slot lane&7; source 16B-group
    // pre-swizzled: (lane&7)^(lane>>3)  [slot s holds global group s^(row&7)]
    const int srow = lane >> 3;
    const int sg16 = (lane & 7) ^ srow;

    f32x4 acc[3][2];
#pragma unroll
    for (int i = 0; i < 3; i++)
#pragma unroll
        for (int j = 0; j < 2; j++) acc[i][j] = f32x4{0.f, 0.f, 0.f, 0.f};

    const unsigned short* Arow[3];
#pragma unroll
    for (int ri = 0; ri < 3; ri++)
        Arow[ri] = Ab + (size_t)(j0 + wj * 48 + ri * 16 + lr) * 1024 + lg * 8;

    bf16x8 Ac[2][3], An[2][3];

    // ---- prologue: stage tiles 0,1 ; load A(0). Per-wave queue: [s0:2][s1:2][A0:6]
#pragma unroll
    for (int i = 0; i < 2; i++) {
        int c = wave + i * 4;
        gload_lds16(Bb + (size_t)(n0 + 8 * c + srow) * 1024 + 0 + sg16 * 8,
                    &Blds[0][c * 512]);
    }
#pragma unroll
    for (int i = 0; i < 2; i++) {
        int c = wave + i * 4;
        gload_lds16(Bb + (size_t)(n0 + 8 * c + srow) * 1024 + 64 + sg16 * 8,
                    &Blds[1][c * 512]);
    }
#pragma unroll
    for (int h = 0; h < 2; h++)
#pragma unroll
        for (int ri = 0; ri < 3; ri++)
            Ac[h][ri] = __builtin_bit_cast(bf16x8,
                *reinterpret_cast<const short8*>(Arow[ri] + h * 32));
    __builtin_amdgcn_sched_barrier(0);
    asm volatile("s_waitcnt vmcnt(8)" ::: "memory");   // own tile-0 staging landed
    __builtin_amdgcn_s_barrier();                      // join -> all waves' landed
    __builtin_amdgcn_sched_barrier(0);

#pragma unroll
    for (int t = 0; t < 16; ++t) {
        // ---- B fragments from swizzled LDS buf t%3
        const unsigned short* ldsB = &Blds[t % 3][0];
        bf16x8 Bfr[2][2];
#pragma unroll
        for (int h = 0; h < 2; h++)
#pragma unroll
            for (int ci = 0; ci < 2; ci++) {
                int row = wn * 32 + ci * 16 + lr;
                int sw  = (h * 4 + lg) ^ (lr & 7);
                Bfr[h][ci] = __builtin_bit_cast(bf16x8,
                    *reinterpret_cast<const short8*>(ldsB + row * 64 + sw * 8));
            }
        // ---- issue stage for tile t+2
        if (t < 14) {
#pragma unroll
            for (int i = 0; i < 2; i++) {
                int c = wave + i * 4;
                gload_lds16(Bb + (size_t)(n0 + 8 * c + srow) * 1024 + (t + 2) * 64 + sg16 * 8,
                            &Blds[(t + 2) % 3][c * 512]);
            }
        }
        // ---- prefetch A for tile t+1
        if (t < 15) {
#pragma unroll
            for (int h = 0; h < 2; h++)
#pragma unroll
                for (int ri = 0; ri < 3; ri++)
                    An[h][ri] = __builtin_bit_cast(bf16x8,
                        *reinterpret_cast<const short8*>(Arow[ri] + (t + 1) * 64 + h * 32));
        }
        // ---- 12 MFMA (compiler's vmcnt for Ac also retires stage(t+1))
#pragma unroll
        for (int h = 0; h < 2; h++)
#pragma unroll
            for (int ri = 0; ri < 3; ri++)
#pragma unroll
                for (int ci = 0; ci < 2; ci++)
                    acc[ri][ci] = __builtin_amdgcn_mfma_f32_16x16x32_bf16(
                        Ac[h][ri], Bfr[h][ci], acc[ri][ci], 0, 0, 0);
#pragma unroll
        for (int h = 0; h < 2; h++)
#pragma unroll
            for (int ri = 0; ri < 3; ri++)
                Ac[h][ri] = An[h][ri];     // SSA-folds under full unroll
        // steady state in flight: stage(t+2):2 + A(t+1):6 = 8
        asm volatile("s_waitcnt vmcnt(8)" ::: "memory");
        __builtin_amdgcn_s_barrier();
        __builtin_amdgcn_sched_barrier(0);
    }

    // ---- epilogue: D layout col = lane&15, row = (lane>>4)*4 + reg
    unsigned short* Cb = Cout + (size_t)b * 192 * 1024;
    const int jw = j0 + wj * 48;
    const int nw = n0 + wn * 32;
#pragma unroll
    for (int ri = 0; ri < 3; ri++)
#pragma unroll
        for (int ci = 0; ci < 2; ci++) {
            int col = nw + ci * 16 + lr;
#pragma unroll
            for (int r = 0; r < 4; r++) {
                int row = jw + ri * 16 + lg * 4 + r;
                Cb[(size_t)row * 1024 + col] = f32_to_bf16(acc[ri][ci][r]);
            }
        }
}

// ---------------------------------------------------------------------------
// final_contract: out[b,n,o,t] = relu( sum_f Th0[f,o]*xT + Th1[f,o]*r1 + Th2[f,o]*r2 )
// block = 192 threads (64 n x 3 tq), out tile staged in padded LDS,
// coalesced float4 copy-out. grid (16 n-chunks, 16 b).
// ---------------------------------------------------------------------------
#define OBUF_STRIDE 196   // 192 + 4 pad

__global__ __launch_bounds__(192)
void final_contract(const unsigned short* __restrict__ xT,
                    const unsigned short* __restrict__ r1,
                    const unsigned short* __restrict__ r2,
                    const float* __restrict__ Theta,   // [3][16][16]
                    float* __restrict__ out)           // [B][1024][16][12]
{
    __shared__ float th[768];
    __shared__ float obuf[64 * OBUF_STRIDE];

    const int tid = threadIdx.x;
    for (int i = tid; i < 768; i += 192) th[i] = Theta[i];
    __syncthreads();

    const int b  = blockIdx.y;
    const int n0 = blockIdx.x * 64;
    const int nl = tid & 63;
    const int tq = tid >> 6;          // 0..2

    float acc[4][16];
#pragma unroll
    for (int tt = 0; tt < 4; tt++)
#pragma unroll
        for (int o = 0; o < 16; o++) acc[tt][o] = 0.f;

    const size_t basep = (size_t)b * 192 * 1024 + n0 + nl;
#pragma unroll
    for (int f = 0; f < 16; f++) {
        size_t off = basep + (size_t)(f * 12 + tq * 4) * 1024;
        float v0[4], v1[4], v2[4];
#pragma unroll
        for (int tt = 0; tt < 4; tt++) {
            v0[tt] = bf16_to_f32(xT[off + (size_t)tt * 1024]);
            v1[tt] = bf16_to_f32(r1[off + (size_t)tt * 1024]);
            v2[tt] = bf16_to_f32(r2[off + (size_t)tt * 1024]);
        }
        const f32x4* t0 = reinterpret_cast<const f32x4*>(&th[0 * 256 + f * 16]);
        const f32x4* t1 = reinterpret_cast<const f32x4*>(&th[1 * 256 + f * 16]);
        const f32x4* t2 = reinterpret_cast<const f32x4*>(&th[2 * 256 + f * 16]);
#pragma unroll
        for (int q = 0; q < 4; q++) {
            f32x4 w0 = t0[q], w1 = t1[q], w2 = t2[q];
#pragma unroll
            for (int tt = 0; tt < 4; tt++)
#pragma unroll
                for (int e = 0; e < 4; e++)
                    acc[tt][q * 4 + e] += v0[tt] * w0[e] + v1[tt] * w1[e] + v2[tt] * w2[e];
        }
    }
#pragma unroll
    for (int o = 0; o < 16; o++) {
        f32x4 v;
#pragma unroll
        for (int tt = 0; tt < 4; tt++) v[tt] = fmaxf(acc[tt][o], 0.f);
        *reinterpret_cast<f32x4*>(&obuf[nl * OBUF_STRIDE + o * 12 + tq * 4]) = v;
    }
    __syncthreads();

    float* outp = out + ((size_t)b * 1024 + n0) * 192;
#pragma unroll
    for (int i = 0; i < 16; i++) {
        int v   = tid + i * 192;
        int row = v / 48;
        int c   = v - row * 48;
        *reinterpret_cast<f32x4*>(&outp[(size_t)v * 4]) =
            *reinterpret_cast<const f32x4*>(&obuf[row * OBUF_STRIDE + c * 4]);
    }
}

// ---------------------------------------------------------------------------
extern "C" void kernel_launch(void* const* d_in, const int* in_sizes, int n_in,
                              void* d_out, int out_size, void* d_ws, size_t ws_size,
                              hipStream_t stream)
{
    const float* x     = (const float*)d_in[0];   // [16][1024][16][12]
    const float* sa    = (const float*)d_in[1];   // [16][1024][1024]
    const float* adj   = (const float*)d_in[2];   // [1024][1024]
    const float* Theta = (const float*)d_in[3];   // [3][16][16]
    float* out = (float*)d_out;

    char* ws = (char*)d_ws;
    const size_t SZ_AT = (size_t)16 * 1024 * 1024 * 2;  // 32 MB
    const size_t SZ_XT = (size_t)16 * 192  * 1024 * 2;  //  6 MB
    unsigned short* aT = (unsigned short*)ws;
    unsigned short* xT = (unsigned short*)(ws + SZ_AT);
    unsigned short* r1 = (unsigned short*)(ws + SZ_AT + SZ_XT);
    unsigned short* r2 = (unsigned short*)(ws + SZ_AT + 2 * SZ_XT);

    prep_a<<<dim3(32, 32, 16), 256, 0, stream>>>(sa, adj, aT);
    prep_x<<<dim3(32, 6, 16), 256, 0, stream>>>(x, xT);
    gemm_tn<<<dim3(16, 2, 16), 256, 0, stream>>>(xT, aT, r1);   // rhs1T
    gemm_tn<<<dim3(16, 2, 16), 256, 0, stream>>>(r1, aT, r2);   // rhs2T
    final_contract<<<dim3(16, 16), 192, 0, stream>>>(xT, r1, r2, Theta, out);
}

// Round 6
// 82.990 us; speedup vs baseline: 1.1464x; 1.1464x over previous
//
#include <hip/hip_runtime.h>
#include <hip/hip_bf16.h>

// ============================================================================
// AdaptiveDiffusionConv: out[b,n,o,t] = relu( sum_{k,f} Theta[k,f,o] * rhs_k )
//   rhs0 = x, rhs1 = a^T x, rhs2 = a^T rhs1   (a = adj .* spatial_attention)
// (a@a)^T x = a^T (a^T x)  -> two [1024x1024]^T @ [1024x192] batched GEMMs.
//
// R6: GEMM back to 96x128 (256 blocks) with a corrected, explicitly-fenced
// 3-deep pipeline: per step [ds_read B] [A(t+1) prefetch] [stage(t+2)]
// [24 MFMA] vmcnt(10)+s_barrier; A prefetched BEFORE stage so the compiler's
// A-wait never drains the staging queue; tail waits fixed (t=14: vmcnt(6)).
// Bijective XCD swizzle (2 batches/XCD = 4MB B = L2). Coalesced C-store
// via LDS-staged tile.
// ============================================================================

typedef __attribute__((ext_vector_type(8))) __bf16 bf16x8;
typedef __attribute__((ext_vector_type(4))) float  f32x4;
typedef __attribute__((ext_vector_type(8))) short  short8;
typedef __attribute__((ext_vector_type(4))) short  s16x4;

__device__ inline unsigned short f32_to_bf16(float f) {
    unsigned int u = __builtin_bit_cast(unsigned int, f);
    unsigned int r = u + 0x7FFFu + ((u >> 16) & 1u);   // RNE
    return (unsigned short)(r >> 16);
}
__device__ inline float bf16_to_f32(unsigned short u) {
    unsigned int x = ((unsigned int)u) << 16;
    return __builtin_bit_cast(float, x);
}

__device__ inline void gload_lds16(const void* gsrc, void* ldst) {
    __builtin_amdgcn_global_load_lds(
        (const __attribute__((address_space(1))) unsigned int*)gsrc,
        (__attribute__((address_space(3))) unsigned int*)ldst,
        16, 0, 0);
}

// ---------------------------------------------------------------------------
// prep_a: aT[b][n][m] = bf16(adj[m][n] * sa[b][m][n]); 32x32 tile transpose.
// float4 loads, s16x4 stores. grid (32 n, 32 m, 16 b) x 256.
// ---------------------------------------------------------------------------
__global__ void prep_a(const float* __restrict__ sa, const float* __restrict__ adj,
                       unsigned short* __restrict__ aT)
{
    __shared__ float tile[32][33];
    const int b  = blockIdx.z;
    const int m0 = blockIdx.y * 32;
    const int n0 = blockIdx.x * 32;
    const int tid = threadIdx.x;
    const int r  = tid >> 3;          // 0..31 (m-local)
    const int c4 = (tid & 7) * 4;     // n-local col group
    const float* sab = sa + (size_t)b * 1024 * 1024;

    size_t idx = (size_t)(m0 + r) * 1024 + (n0 + c4);
    f32x4 av = *reinterpret_cast<const f32x4*>(&adj[idx]);
    f32x4 sv = *reinterpret_cast<const f32x4*>(&sab[idx]);
#pragma unroll
    for (int k = 0; k < 4; k++) tile[r][c4 + k] = av[k] * sv[k];
    __syncthreads();

    unsigned short* aTb = aT + (size_t)b * 1024 * 1024;
    const int nl = tid >> 3;          // n-local row
    const int m4 = (tid & 7) * 4;     // m-local col group
    s16x4 v;
#pragma unroll
    for (int k = 0; k < 4; k++) v[k] = (short)f32_to_bf16(tile[m4 + k][nl]);
    *reinterpret_cast<s16x4*>(&aTb[(size_t)(n0 + nl) * 1024 + m0 + m4]) = v;
}

// ---------------------------------------------------------------------------
// prep_x: xT[b][j][m] = bf16(x[b][m][j]), j = f*12+t (192). float4 loads.
// grid (32 m, 6 j, 16 b) x 256.
// ---------------------------------------------------------------------------
__global__ void prep_x(const float* __restrict__ x, unsigned short* __restrict__ xT)
{
    __shared__ float tile[32][33];
    const int b  = blockIdx.z;
    const int j0 = blockIdx.y * 32;
    const int m0 = blockIdx.x * 32;
    const int tid = threadIdx.x;
    const int r  = tid >> 3;          // m-local
    const int c4 = (tid & 7) * 4;     // j-local
    const float* xb = x + (size_t)b * 1024 * 192;

    f32x4 v = *reinterpret_cast<const f32x4*>(&xb[(size_t)(m0 + r) * 192 + j0 + c4]);
#pragma unroll
    for (int k = 0; k < 4; k++) tile[r][c4 + k] = v[k];
    __syncthreads();

    unsigned short* xTb = xT + (size_t)b * 192 * 1024;
    const int jl = tid >> 3;
    const int m4 = (tid & 7) * 4;
    s16x4 o;
#pragma unroll
    for (int k = 0; k < 4; k++) o[k] = (short)f32_to_bf16(tile[m4 + k][jl]);
    *reinterpret_cast<s16x4*>(&xTb[(size_t)(j0 + jl) * 1024 + m0 + m4]) = o;
}

// ---------------------------------------------------------------------------
// gemm_tn: Cout[b][j][n] (bf16) = sum_m Aop[b][j][m] * Bop[b][n][m]
// tile 96j x 128n, BK=64, 4 waves (2x2), wave tile 48x64 (24 MFMA/step).
// 3 LDS buffers (48KB), raw s_barrier + counted vmcnt; A prefetched BEFORE
// stage each step so no wait ever drains the queue.
// grid 256 blocks (XCD-swizzled: 2 contiguous batches per XCD).
// ---------------------------------------------------------------------------
__global__ __launch_bounds__(256, 1)
void gemm_tn(const unsigned short* __restrict__ Aop,
             const unsigned short* __restrict__ Bop,
             unsigned short* __restrict__ Cout)
{
    // bijective XCD swizzle over 256 blocks: XCD x -> 32 contiguous ids
    const int lin = blockIdx.x + 8 * (blockIdx.y + 2 * blockIdx.z);
    const int swz = (lin & 7) * 32 + (lin >> 3);
    const int nb  = swz & 7;
    const int jb  = (swz >> 3) & 1;
    const int b   = swz >> 4;

    const int j0 = jb * 96;
    const int n0 = nb * 128;
    const unsigned short* Ab = Aop + (size_t)b * 192 * 1024;
    const unsigned short* Bb = Bop + (size_t)b * 1024 * 1024;

    __shared__ unsigned short Blds[3][128 * 64];   // 3 x 16KB, linear

    const int tid  = threadIdx.x;
    const int lane = tid & 63;
    const int wave = tid >> 6;      // 0..3
    const int wj   = wave >> 1;     // 0..1 -> 48j
    const int wn   = wave & 1;      // 0..1 -> 64n
    const int lr   = lane & 15;
    const int lg   = lane >> 4;     // 0..3

    // staging: chunk c = rows 8c..8c+7 (1KB); lane -> row 8c+(lane>>3),
    // dest slot lane&7; source 16B-group pre-swizzled: (lane&7)^(lane>>3)
    const int srow = lane >> 3;
    const int sg16 = (lane & 7) ^ srow;

    f32x4 acc[3][4];
#pragma unroll
    for (int i = 0; i < 3; i++)
#pragma unroll
        for (int j = 0; j < 4; j++) acc[i][j] = f32x4{0.f, 0.f, 0.f, 0.f};

    const unsigned short* Arow[3];
#pragma unroll
    for (int ri = 0; ri < 3; ri++)
        Arow[ri] = Ab + (size_t)(j0 + wj * 48 + ri * 16 + lr) * 1024 + lg * 8;

    bf16x8 Ac[2][3], An[2][3];

    // ---- prologue: stage(0):4, stage(1):4, A(0):6 -> vmcnt(10) retires stage(0)
#pragma unroll
    for (int i = 0; i < 4; i++) {
        int c = wave * 4 + i;
        gload_lds16(Bb + (size_t)(n0 + 8 * c + srow) * 1024 + 0 + sg16 * 8,
                    &Blds[0][c * 512]);
    }
#pragma unroll
    for (int i = 0; i < 4; i++) {
        int c = wave * 4 + i;
        gload_lds16(Bb + (size_t)(n0 + 8 * c + srow) * 1024 + 64 + sg16 * 8,
                    &Blds[1][c * 512]);
    }
#pragma unroll
    for (int h = 0; h < 2; h++)
#pragma unroll
        for (int ri = 0; ri < 3; ri++)
            Ac[h][ri] = __builtin_bit_cast(bf16x8,
                *reinterpret_cast<const short8*>(Arow[ri] + h * 32));
    __builtin_amdgcn_sched_barrier(0);
    asm volatile("s_waitcnt vmcnt(10)" ::: "memory");
    __builtin_amdgcn_s_barrier();
    __builtin_amdgcn_sched_barrier(0);

#pragma unroll
    for (int t = 0; t < 16; ++t) {
        // S1: B fragments (8x ds_read_b128) from swizzled buf t%3
        const unsigned short* ldsB = &Blds[t % 3][0];
        bf16x8 Bfr[2][4];
#pragma unroll
        for (int h = 0; h < 2; h++)
#pragma unroll
            for (int ci = 0; ci < 4; ci++) {
                int row = wn * 64 + ci * 16 + lr;
                int sw  = (h * 4 + lg) ^ (lr & 7);
                Bfr[h][ci] = __builtin_bit_cast(bf16x8,
                    *reinterpret_cast<const short8*>(ldsB + row * 64 + sw * 8));
            }
        __builtin_amdgcn_sched_barrier(0);
        // S2: A(t+1) prefetch (6 loads) -- BEFORE stage so A-wait != drain
        if (t < 15) {
#pragma unroll
            for (int h = 0; h < 2; h++)
#pragma unroll
                for (int ri = 0; ri < 3; ri++)
                    An[h][ri] = __builtin_bit_cast(bf16x8,
                        *reinterpret_cast<const short8*>(Arow[ri] + (t + 1) * 64 + h * 32));
        }
        __builtin_amdgcn_sched_barrier(0);
        // S3: stage(t+2) (4 gload_lds)
        if (t < 14) {
#pragma unroll
            for (int i = 0; i < 4; i++) {
                int c = wave * 4 + i;
                gload_lds16(Bb + (size_t)(n0 + 8 * c + srow) * 1024 + (t + 2) * 64 + sg16 * 8,
                            &Blds[(t + 2) % 3][c * 512]);
            }
        }
        __builtin_amdgcn_sched_barrier(0);
        // S4: 24 MFMA (compiler waits lgkm for Bfr; vmcnt(14) retires A(t) only)
#pragma unroll
        for (int h = 0; h < 2; h++)
#pragma unroll
            for (int ri = 0; ri < 3; ri++)
#pragma unroll
                for (int ci = 0; ci < 4; ci++)
                    acc[ri][ci] = __builtin_amdgcn_mfma_f32_16x16x32_bf16(
                        Ac[h][ri], Bfr[h][ci], acc[ri][ci], 0, 0, 0);
#pragma unroll
        for (int h = 0; h < 2; h++)
#pragma unroll
            for (int ri = 0; ri < 3; ri++)
                Ac[h][ri] = An[h][ri];
        // end-of-step: retire stage(t+1) exactly; never drain
        if (t < 14) {
            asm volatile("s_waitcnt vmcnt(10)" ::: "memory");
            __builtin_amdgcn_s_barrier();
            __builtin_amdgcn_sched_barrier(0);
        } else if (t == 14) {
            asm volatile("s_waitcnt vmcnt(6)" ::: "memory");   // stage(15) landed
            __builtin_amdgcn_s_barrier();
            __builtin_amdgcn_sched_barrier(0);
        }
    }

    // ---- epilogue: stage C-tile (96x128 bf16) in LDS, coalesced b128 stores
    __syncthreads();   // all waves done reading buf0 before reuse
    unsigned short* cl = (unsigned short*)&Blds[0][0];
#pragma unroll
    for (int ri = 0; ri < 3; ri++)
#pragma unroll
        for (int ci = 0; ci < 4; ci++) {
            int col = wn * 64 + ci * 16 + lr;
#pragma unroll
            for (int r = 0; r < 4; r++) {
                int row = wj * 48 + ri * 16 + lg * 4 + r;
                cl[row * 128 + col] = f32_to_bf16(acc[ri][ci][r]);
            }
        }
    __syncthreads();
    unsigned short* Cb = Cout + (size_t)b * 192 * 1024;
#pragma unroll
    for (int i = 0; i < 6; i++) {
        int idx = tid + i * 256;          // 1536 16B chunks
        int row = idx >> 4;
        int c16 = idx & 15;
        *reinterpret_cast<short8*>(Cb + (size_t)(j0 + row) * 1024 + n0 + c16 * 8) =
            *reinterpret_cast<const short8*>(cl + row * 128 + c16 * 8);
    }
}

// ---------------------------------------------------------------------------
// final_contract: out[b,n,o,t] = relu( sum_f Th0[f,o]*xT + Th1[f,o]*r1 + Th2[f,o]*r2 )
// block = 192 threads (64 n x 3 tq), out tile staged in padded LDS,
// coalesced float4 copy-out. grid (16 n-chunks, 16 b).
// ---------------------------------------------------------------------------
#define OBUF_STRIDE 196   // 192 + 4 pad

__global__ __launch_bounds__(192)
void final_contract(const unsigned short* __restrict__ xT,
                    const unsigned short* __restrict__ r1,
                    const unsigned short* __restrict__ r2,
                    const float* __restrict__ Theta,   // [3][16][16]
                    float* __restrict__ out)           // [B][1024][16][12]
{
    __shared__ float th[768];
    __shared__ float obuf[64 * OBUF_STRIDE];

    const int tid = threadIdx.x;
    for (int i = tid; i < 768; i += 192) th[i] = Theta[i];
    __syncthreads();

    const int b  = blockIdx.y;
    const int n0 = blockIdx.x * 64;
    const int nl = tid & 63;
    const int tq = tid >> 6;          // 0..2

    float acc[4][16];
#pragma unroll
    for (int tt = 0; tt < 4; tt++)
#pragma unroll
        for (int o = 0; o < 16; o++) acc[tt][o] = 0.f;

    const size_t basep = (size_t)b * 192 * 1024 + n0 + nl;
#pragma unroll
    for (int f = 0; f < 16; f++) {
        size_t off = basep + (size_t)(f * 12 + tq * 4) * 1024;
        float v0[4], v1[4], v2[4];
#pragma unroll
        for (int tt = 0; tt < 4; tt++) {
            v0[tt] = bf16_to_f32(xT[off + (size_t)tt * 1024]);
            v1[tt] = bf16_to_f32(r1[off + (size_t)tt * 1024]);
            v2[tt] = bf16_to_f32(r2[off + (size_t)tt * 1024]);
        }
        const f32x4* t0 = reinterpret_cast<const f32x4*>(&th[0 * 256 + f * 16]);
        const f32x4* t1 = reinterpret_cast<const f32x4*>(&th[1 * 256 + f * 16]);
        const f32x4* t2 = reinterpret_cast<const f32x4*>(&th[2 * 256 + f * 16]);
#pragma unroll
        for (int q = 0; q < 4; q++) {
            f32x4 w0 = t0[q], w1 = t1[q], w2 = t2[q];
#pragma unroll
            for (int tt = 0; tt < 4; tt++)
#pragma unroll
                for (int e = 0; e < 4; e++)
                    acc[tt][q * 4 + e] += v0[tt] * w0[e] + v1[tt] * w1[e] + v2[tt] * w2[e];
        }
    }
#pragma unroll
    for (int o = 0; o < 16; o++) {
        f32x4 v;
#pragma unroll
        for (int tt = 0; tt < 4; tt++) v[tt] = fmaxf(acc[tt][o], 0.f);
        *reinterpret_cast<f32x4*>(&obuf[nl * OBUF_STRIDE + o * 12 + tq * 4]) = v;
    }
    __syncthreads();

    float* outp = out + ((size_t)b * 1024 + n0) * 192;
#pragma unroll
    for (int i = 0; i < 16; i++) {
        int v   = tid + i * 192;
        int row = v / 48;
        int c   = v - row * 48;
        *reinterpret_cast<f32x4*>(&outp[(size_t)v * 4]) =
            *reinterpret_cast<const f32x4*>(&obuf[row * OBUF_STRIDE + c * 4]);
    }
}

// ---------------------------------------------------------------------------
extern "C" void kernel_launch(void* const* d_in, const int* in_sizes, int n_in,
                              void* d_out, int out_size, void* d_ws, size_t ws_size,
                              hipStream_t stream)
{
    const float* x     = (const float*)d_in[0];   // [16][1024][16][12]
    const float* sa    = (const float*)d_in[1];   // [16][1024][1024]
    const float* adj   = (const float*)d_in[2];   // [1024][1024]
    const float* Theta = (const float*)d_in[3];   // [3][16][16]
    float* out = (float*)d_out;

    char* ws = (char*)d_ws;
    const size_t SZ_AT = (size_t)16 * 1024 * 1024 * 2;  // 32 MB
    const size_t SZ_XT = (size_t)16 * 192  * 1024 * 2;  //  6 MB
    unsigned short* aT = (unsigned short*)ws;
    unsigned short* xT = (unsigned short*)(ws + SZ_AT);
    unsigned short* r1 = (unsigned short*)(ws + SZ_AT + SZ_XT);
    unsigned short* r2 = (unsigned short*)(ws + SZ_AT + 2 * SZ_XT);

    prep_a<<<dim3(32, 32, 16), 256, 0, stream>>>(sa, adj, aT);
    prep_x<<<dim3(32, 6, 16), 256, 0, stream>>>(x, xT);
    gemm_tn<<<dim3(8, 2, 16), 256, 0, stream>>>(xT, aT, r1);   // rhs1T
    gemm_tn<<<dim3(8, 2, 16), 256, 0, stream>>>(r1, aT, r2);   // rhs2T
    final_contract<<<dim3(16, 16), 192, 0, stream>>>(xT, r1, r2, Theta, out);
}